// Round 7
// baseline (14680.612 us; speedup 1.0000x reference)
//
#include <hip/hip_runtime.h>
#include <math.h>

// Elman RNN persistent kernel, R7: seq-embedded h + barrier-free half-wave chains.
// batch=64, T=2048, in=256, hidden=512, out=256, fp32.
// 256 blocks = 4 batch-groups(16 rows) x 64 col-groups(8 h-cols, 4 y-cols).
// Half-wave (r2=tid>>5, lanes g=0..31) is an INDEPENDENT unit owning rows
// {R0+r2, R0+r2+8} x cols {C0..C0+7}: weights in regs (w1r 192 + w2r 64 VGPR),
// k-reduce via __shfl_xor butterfly (no LDS, no __syncthreads anywhere in loop).
// h exchange: u64 pairs (float h, uint seq=t+1) in ping-pong hbuf[2];
// consumers retry-load until seq==t -> data IS the flag (no tags, no vmcnt
// drain, 1 visibility latency per step). Depth-2 safe: seq t+1 visible on all
// pairs => all producers' h_t loads returned (data dependence thru FMA chain).
// Init zeroes BOTH buffers each launch (stale seq from prev replay would
// alias at t==2047). Numerics: recurrence fp32 (error amp ~1e4, R1).

#define BB 64
#define TT 2048
#define II 256
#define HH 512
#define OO 256
#define NBLK 256
#define OUT_OFF ((size_t)BB * TT * OO)

typedef unsigned long long ull;
#define F4C(v,i) ((i)==0?(v).x:((i)==1?(v).y:((i)==2?(v).z:(v).w)))

__device__ inline float u2f(unsigned u) { return __builtin_bit_cast(float, u); }

__global__ void rnn_init(ull* __restrict__ hbuf) {
    int i = blockIdx.x * blockDim.x + threadIdx.x;   // 256x256 = 65536 = 2*BB*HH
    hbuf[i] = 0ull;                                  // (h=0.0f, seq=0)
}

__global__ __launch_bounds__(256, 1) void rnn_persist(
    const float* __restrict__ x, const float* __restrict__ W1,
    const float* __restrict__ b1, const float* __restrict__ W2,
    const float* __restrict__ b2, float* __restrict__ out,
    ull* __restrict__ hbuf)
{
    const int tid = threadIdx.x;
    const int blk = blockIdx.x;
    const int bi  = blk >> 6;             // batch group (16 rows)
    const int cj  = blk & 63;             // col group
    const int R0  = bi << 4;
    const int C0  = cj << 3;              // 8 h-cols
    const int O0  = cj << 2;              // 4 y-cols

    const int g  = tid & 31;              // k-slice lane within half-wave
    const int r2 = tid >> 5;              // half-wave id: rows R0+r2, R0+r2+8

    // ---- weights into registers (one-time; same mapping as R5/R6) ----
    float w1r[6][4][8];
    #pragma unroll
    for (int j = 0; j < 6; ++j)
        #pragma unroll
        for (int i = 0; i < 4; ++i) {
            const float* wp = W1 + (size_t)(j * 128 + (g << 2) + i) * HH + C0;
            float4 a = *(const float4*)wp;
            float4 b = *(const float4*)(wp + 4);
            w1r[j][i][0] = a.x; w1r[j][i][1] = a.y; w1r[j][i][2] = a.z; w1r[j][i][3] = a.w;
            w1r[j][i][4] = b.x; w1r[j][i][5] = b.y; w1r[j][i][6] = b.z; w1r[j][i][7] = b.w;
        }
    float w2r[4][4][4];
    #pragma unroll
    for (int j = 0; j < 4; ++j)
        #pragma unroll
        for (int i = 0; i < 4; ++i) {
            float4 a = *(const float4*)(W2 + (size_t)(j * 128 + (g << 2) + i) * OO + O0);
            w2r[j][i][0] = a.x; w2r[j][i][1] = a.y; w2r[j][i][2] = a.z; w2r[j][i][3] = a.w;
        }
    const float b1v = b1[C0 + (g & 7)];                       // publish lanes g<16
    const float b2v = b2[O0 + (g & 3)];                       // y lanes g in [16,24)

    ull* hb[2] = { hbuf, hbuf + (size_t)BB * HH };
    const int row0 = R0 + r2;             // local rows: row0, row0+8

    for (int t = 0; t < TT; ++t) {
        // ---- x_t direct-to-reg (independent; issue before retry loop) ----
        float4 xreg[2][2];
        #pragma unroll
        for (int rr = 0; rr < 2; ++rr)
            #pragma unroll
            for (int jx = 0; jx < 2; ++jx)
                xreg[rr][jx] = *(const float4*)&x[((size_t)(row0 + (rr << 3)) * TT + t) * II
                                                  + jx * 128 + (g << 2)];

        // ---- h_t retry-load: all 32 pairs must carry seq==t ----
        float4 hreg[2][4];
        {
            const ull* hsrc = hb[t & 1];
            int bad;
            do {
                bad = 0;
                #pragma unroll
                for (int rr = 0; rr < 2; ++rr)
                    #pragma unroll
                    for (int j = 0; j < 4; ++j) {
                        const ull* bp = hsrc + (size_t)(row0 + (rr << 3)) * HH
                                             + (j << 7) + (g << 2);
                        ull p0 = __hip_atomic_load(bp + 0, __ATOMIC_RELAXED, __HIP_MEMORY_SCOPE_AGENT);
                        ull p1 = __hip_atomic_load(bp + 1, __ATOMIC_RELAXED, __HIP_MEMORY_SCOPE_AGENT);
                        ull p2 = __hip_atomic_load(bp + 2, __ATOMIC_RELAXED, __HIP_MEMORY_SCOPE_AGENT);
                        ull p3 = __hip_atomic_load(bp + 3, __ATOMIC_RELAXED, __HIP_MEMORY_SCOPE_AGENT);
                        bad |= (int)((unsigned)(p0 >> 32) != (unsigned)t);
                        bad |= (int)((unsigned)(p1 >> 32) != (unsigned)t);
                        bad |= (int)((unsigned)(p2 >> 32) != (unsigned)t);
                        bad |= (int)((unsigned)(p3 >> 32) != (unsigned)t);
                        hreg[rr][j] = make_float4(u2f((unsigned)p0), u2f((unsigned)p1),
                                                  u2f((unsigned)p2), u2f((unsigned)p3));
                    }
            } while (__builtin_expect(bad != 0, 0));
        }

        // ---- A-GEMM (K=768) and Y-GEMM (K=512) from regs ----
        float pa[2][8];
        float py[2][4];
        #pragma unroll
        for (int rr = 0; rr < 2; ++rr) {
            #pragma unroll
            for (int c = 0; c < 8; ++c) pa[rr][c] = 0.f;
            #pragma unroll
            for (int o = 0; o < 4; ++o) py[rr][o] = 0.f;
        }
        #pragma unroll
        for (int rr = 0; rr < 2; ++rr) {
            #pragma unroll
            for (int j = 0; j < 6; ++j) {
                float4 vv = (j < 4) ? hreg[rr][j] : xreg[rr][j - 4];
                #pragma unroll
                for (int i = 0; i < 4; ++i) {
                    const float vi = F4C(vv, i);
                    #pragma unroll
                    for (int c = 0; c < 8; ++c)
                        pa[rr][c] = fmaf(vi, w1r[j][i][c], pa[rr][c]);
                }
            }
            if (t > 0) {
                #pragma unroll
                for (int j = 0; j < 4; ++j) {
                    float4 vv = hreg[rr][j];
                    #pragma unroll
                    for (int i = 0; i < 4; ++i) {
                        const float vi = F4C(vv, i);
                        #pragma unroll
                        for (int o = 0; o < 4; ++o)
                            py[rr][o] = fmaf(vi, w2r[j][i][o], py[rr][o]);
                    }
                }
            }
        }

        // ---- butterfly k-reduce over the 32 half-wave lanes ----
        #pragma unroll
        for (int rr = 0; rr < 2; ++rr)
            #pragma unroll
            for (int c = 0; c < 8; ++c) {
                float v = pa[rr][c];
                v += __shfl_xor(v, 1);  v += __shfl_xor(v, 2);
                v += __shfl_xor(v, 4);  v += __shfl_xor(v, 8);
                v += __shfl_xor(v, 16);
                pa[rr][c] = v;
            }
        if (t > 0) {
            #pragma unroll
            for (int rr = 0; rr < 2; ++rr)
                #pragma unroll
                for (int o = 0; o < 4; ++o) {
                    float v = py[rr][o];
                    v += __shfl_xor(v, 1);  v += __shfl_xor(v, 2);
                    v += __shfl_xor(v, 4);  v += __shfl_xor(v, 8);
                    v += __shfl_xor(v, 16);
                    py[rr][o] = v;
                }
        }

        // ---- publish h_{t+1}: lanes 0..15 -> (row0 + (g&8), col C0+(g&7)) ----
        if (g < 16) {
            float hsum = pa[0][0];
            #pragma unroll
            for (int rr = 0; rr < 2; ++rr)
                #pragma unroll
                for (int c = 0; c < 8; ++c)
                    if (g == ((rr << 3) | c)) hsum = pa[rr][c];
            float hv = tanhf(hsum + b1v);
            const int row = row0 + (g & 8);
            ull pk = (ull)__builtin_bit_cast(unsigned, hv) | ((ull)(unsigned)(t + 1) << 32);
            __hip_atomic_store(&hb[(t + 1) & 1][(size_t)row * HH + C0 + (g & 7)], pk,
                               __ATOMIC_RELAXED, __HIP_MEMORY_SCOPE_AGENT);
            if (t == TT - 1)
                out[OUT_OFF + (size_t)row * HH + C0 + (g & 7)] = hv;
        }
        // ---- y_{t-1}: lanes 16..23 -> (row0 + 8*(q>>2), col O0+(q&3)) ----
        if (t > 0 && g >= 16 && g < 24) {
            const int q = g & 7;
            float ysum = py[0][0];
            #pragma unroll
            for (int rr = 0; rr < 2; ++rr)
                #pragma unroll
                for (int o = 0; o < 4; ++o)
                    if (q == ((rr << 2) | o)) ysum = py[rr][o];
            const int row = row0 + ((q >> 2) << 3);
            out[((size_t)row * TT + (t - 1)) * OO + O0 + (q & 3)] = ysum + b2v;
        }
    }

    // ---- epilogue: y_{TT-1} from h_TT (seq==TT in hb[0]) ----
    {
        float4 hreg[2][4];
        const ull* hsrc = hb[TT & 1];
        int bad;
        do {
            bad = 0;
            #pragma unroll
            for (int rr = 0; rr < 2; ++rr)
                #pragma unroll
                for (int j = 0; j < 4; ++j) {
                    const ull* bp = hsrc + (size_t)(row0 + (rr << 3)) * HH
                                         + (j << 7) + (g << 2);
                    ull p0 = __hip_atomic_load(bp + 0, __ATOMIC_RELAXED, __HIP_MEMORY_SCOPE_AGENT);
                    ull p1 = __hip_atomic_load(bp + 1, __ATOMIC_RELAXED, __HIP_MEMORY_SCOPE_AGENT);
                    ull p2 = __hip_atomic_load(bp + 2, __ATOMIC_RELAXED, __HIP_MEMORY_SCOPE_AGENT);
                    ull p3 = __hip_atomic_load(bp + 3, __ATOMIC_RELAXED, __HIP_MEMORY_SCOPE_AGENT);
                    bad |= (int)((unsigned)(p0 >> 32) != (unsigned)TT);
                    bad |= (int)((unsigned)(p1 >> 32) != (unsigned)TT);
                    bad |= (int)((unsigned)(p2 >> 32) != (unsigned)TT);
                    bad |= (int)((unsigned)(p3 >> 32) != (unsigned)TT);
                    hreg[rr][j] = make_float4(u2f((unsigned)p0), u2f((unsigned)p1),
                                              u2f((unsigned)p2), u2f((unsigned)p3));
                }
        } while (__builtin_expect(bad != 0, 0));

        float py[2][4];
        #pragma unroll
        for (int rr = 0; rr < 2; ++rr) {
            #pragma unroll
            for (int o = 0; o < 4; ++o) py[rr][o] = 0.f;
            #pragma unroll
            for (int j = 0; j < 4; ++j) {
                float4 vv = hreg[rr][j];
                #pragma unroll
                for (int i = 0; i < 4; ++i) {
                    const float vi = F4C(vv, i);
                    #pragma unroll
                    for (int o = 0; o < 4; ++o)
                        py[rr][o] = fmaf(vi, w2r[j][i][o], py[rr][o]);
                }
            }
        }
        #pragma unroll
        for (int rr = 0; rr < 2; ++rr)
            #pragma unroll
            for (int o = 0; o < 4; ++o) {
                float v = py[rr][o];
                v += __shfl_xor(v, 1);  v += __shfl_xor(v, 2);
                v += __shfl_xor(v, 4);  v += __shfl_xor(v, 8);
                v += __shfl_xor(v, 16);
                py[rr][o] = v;
            }
        if (g >= 16 && g < 24) {
            const int q = g & 7;
            float ysum = py[0][0];
            #pragma unroll
            for (int rr = 0; rr < 2; ++rr)
                #pragma unroll
                for (int o = 0; o < 4; ++o)
                    if (q == ((rr << 2) | o)) ysum = py[rr][o];
            const int row = row0 + ((q >> 2) << 3);
            out[((size_t)row * TT + (TT - 1)) * OO + O0 + (q & 3)] = ysum + b2v;
        }
    }
}

extern "C" void kernel_launch(void* const* d_in, const int* in_sizes, int n_in,
                              void* d_out, int out_size, void* d_ws, size_t ws_size,
                              hipStream_t stream) {
    const float* x  = (const float*)d_in[0];
    const float* W1 = (const float*)d_in[1];
    const float* b1 = (const float*)d_in[2];
    const float* W2 = (const float*)d_in[3];
    const float* b2 = (const float*)d_in[4];
    float* out = (float*)d_out;

    ull* hbuf = (ull*)d_ws;   // 2 * 64*512 u64 = 512 KB

    rnn_init<<<dim3(256), dim3(256), 0, stream>>>(hbuf);
    rnn_persist<<<dim3(NBLK), dim3(256), 0, stream>>>(x, W1, b1, W2, b2, out, hbuf);
}